// Round 1
// baseline (274.865 us; speedup 1.0000x reference)
//
#include <hip/hip_runtime.h>
#include <cfloat>
#include <cmath>

#define NB 8
#define NA 49104
#define NM 50
#define NC 90

// ws layout (floats): [0..7] cls_sum, [8..15] reg_sum, [16..23] num_pos
// All accumulated via device-scope float atomicAdd (counts exact in f32).

__device__ __forceinline__ float clipc(float x) {
    return fminf(fmaxf(x, 1e-4f), 1.0f - 1e-4f);
}

// Block reduction: wave64 shuffle then LDS across waves. Result valid on tid 0.
__device__ __forceinline__ float block_reduce(float v, float* red) {
#pragma unroll
    for (int o = 32; o > 0; o >>= 1) v += __shfl_down(v, o, 64);
    const int wave = threadIdx.x >> 6;
    const int lane = threadIdx.x & 63;
    if (lane == 0) red[wave] = v;
    __syncthreads();
    float r = 0.f;
    if (threadIdx.x == 0) {
        const int nw = blockDim.x >> 6;
        for (int w = 0; w < nw; ++w) r += red[w];
    }
    __syncthreads();  // allow red reuse by a later call
    return r;
}

// Kernel A: per-anchor IoU assignment, pos mask, smooth-L1 reg sum,
// and classification correction term at the assigned label.
__global__ __launch_bounds__(256) void assign_kernel(
    const float* __restrict__ boxes,      // [B,M,4] x1y1x2y2
    const int*   __restrict__ labels,     // [B,M], 0 = padding
    const float* __restrict__ regression, // [B,A,4]
    const float* __restrict__ cls,        // [B,A,C]
    const float* __restrict__ anchors,    // [A,4] y1x1y2x2
    float* __restrict__ ws) {
    __shared__ float4 sbox[NM];
    __shared__ float  sarea[NM];
    __shared__ int    slab[NM];
    __shared__ float  red[4];

    const int b = blockIdx.y;
    const int t = threadIdx.x;
    if (t < NM) {
        float4 bx = ((const float4*)boxes)[b * NM + t];
        const int l = labels[b * NM + t];
        float area = (bx.z - bx.x) * (bx.w - bx.y);
        if (l == 0) {
            // Invalid box: degenerate coords force inter=0 -> iou=0.
            // Output-equivalent to the reference's -1 mask: iou 0 < 0.15
            // so pos=false either way; ties at 0 only occur when !pos,
            // where alab/assigned are unused.
            bx.x = bx.y = bx.z = bx.w = 3e38f;
            area = 0.f;
        }
        sbox[t]  = bx;
        sarea[t] = area;
        slab[t]  = (l != 0) ? (l - 1) : 0;
    }
    __syncthreads();

    float corr = 0.f, regs = 0.f, npos = 0.f;
    const int a = blockIdx.x * blockDim.x + t;
    if (a < NA) {
        const float4 an = ((const float4*)anchors)[a];
        const float ay1 = an.x, ax1 = an.y, ay2 = an.z, ax2 = an.w;
        const float aarea = (ay2 - ay1) * (ax2 - ax1);

        float best = -1.f;
        int arg = 0;
        for (int m = 0; m < NM; ++m) {
            const float4 bx = sbox[m];  // broadcast b128, conflict-free
            float iw = fminf(ax2, bx.z) - fmaxf(ax1, bx.x);
            float ih = fminf(ay2, bx.w) - fmaxf(ay1, bx.y);
            iw = fmaxf(iw, 0.f);
            ih = fmaxf(ih, 0.f);
            const float inter = iw * ih;
            const float ua = fmaxf(aarea + sarea[m] - inter, 1e-8f);
            const float iou = inter / ua;
            if (iou > best) { best = iou; arg = m; }  // first-occurrence argmax
        }

        const bool big = sarea[arg] > 100.0f;
        const bool pos = big ? (best >= 0.5f) : (best >= 0.15f);
        if (pos) {
            npos = 1.f;
            const float4 bx = sbox[arg];
            const float aw = ax2 - ax1, ah = ay2 - ay1;
            const float acx = ax1 + 0.5f * aw, acy = ay1 + 0.5f * ah;
            const float gw0 = bx.z - bx.x, gh0 = bx.w - bx.y;
            const float gcx = bx.x + 0.5f * gw0, gcy = bx.y + 0.5f * gh0;
            const float gw = fmaxf(gw0, 1.f), gh = fmaxf(gh0, 1.f);
            const float4 r = ((const float4*)regression)[b * NA + a];
            const float tdy = (gcy - acy) / ah;
            const float tdx = (gcx - acx) / aw;
            const float tdh = logf(gh / ah);
            const float tdw = logf(gw / aw);
            const float d0 = fabsf(tdy - r.x);
            const float d1 = fabsf(tdx - r.y);
            const float d2 = fabsf(tdh - r.z);
            const float d3 = fabsf(tdw - r.w);
            regs  = (d0 <= 1.f / 9.f) ? 4.5f * d0 * d0 : d0 - (0.5f / 9.f);
            regs += (d1 <= 1.f / 9.f) ? 4.5f * d1 * d1 : d1 - (0.5f / 9.f);
            regs += (d2 <= 1.f / 9.f) ? 4.5f * d2 * d2 : d2 - (0.5f / 9.f);
            regs += (d3 <= 1.f / 9.f) ? 4.5f * d3 * d3 : d3 - (0.5f / 9.f);

            const int alab = slab[arg];
            const float c = clipc(cls[((size_t)b * NA + a) * NC + alab]);
            const float omc = 1.f - c;
            // replace the negative term with the positive term at (a, alab)
            corr = 0.25f * omc * omc * (-logf(c)) - 0.75f * c * c * (-logf(omc));
        }
    }

    const float tc = block_reduce(corr, red);
    const float tr = block_reduce(regs, red);
    const float tn = block_reduce(npos, red);
    if (threadIdx.x == 0) {
        atomicAdd(&ws[b], tc);
        atomicAdd(&ws[NB + b], tr);
        atomicAdd(&ws[2 * NB + b], tn);
    }
}

// Kernel B: streaming sum of the negative focal term over all B*A*C elements.
__global__ __launch_bounds__(256) void cls_neg_kernel(
    const float* __restrict__ cls, float* __restrict__ ws) {
    __shared__ float red[4];
    const int b = blockIdx.y;
    const float4* p = (const float4*)(cls + (size_t)b * NA * NC);
    const int n4 = NA * NC / 4;  // 1,104,840 (divisible by 4)
    float acc = 0.f;
    for (int i = blockIdx.x * blockDim.x + threadIdx.x; i < n4;
         i += gridDim.x * blockDim.x) {
        const float4 v = p[i];
        const float c0 = clipc(v.x), c1 = clipc(v.y);
        const float c2 = clipc(v.z), c3 = clipc(v.w);
        acc += 0.75f * c0 * c0 * (-logf(1.f - c0));
        acc += 0.75f * c1 * c1 * (-logf(1.f - c1));
        acc += 0.75f * c2 * c2 * (-logf(1.f - c2));
        acc += 0.75f * c3 * c3 * (-logf(1.f - c3));
    }
    const float tot = block_reduce(acc, red);
    if (threadIdx.x == 0) atomicAdd(&ws[b], tot);
}

// Kernel C: finalize the two scalar outputs.
__global__ void finalize_kernel(const float* __restrict__ ws,
                                float* __restrict__ out) {
    if (threadIdx.x == 0 && blockIdx.x == 0) {
        float cl = 0.f, rl = 0.f;
        for (int b = 0; b < NB; ++b) {
            const float np = ws[2 * NB + b];
            cl += ws[b] / fmaxf(np, 1.f);
            rl += (np > 0.f) ? ws[NB + b] / (np * 4.f) : 0.f;
        }
        out[0] = cl / (float)NB;
        out[1] = rl / (float)NB * 50.f;
    }
}

extern "C" void kernel_launch(void* const* d_in, const int* in_sizes, int n_in,
                              void* d_out, int out_size, void* d_ws,
                              size_t ws_size, hipStream_t stream) {
    const float* boxes      = (const float*)d_in[0];  // [B,M,4] f32
    const int*   labels     = (const int*)d_in[1];    // [B,M] i32
    const float* regression = (const float*)d_in[2];  // [B,A,4] f32
    const float* cls        = (const float*)d_in[3];  // [B,A,C] f32
    const float* anchors    = (const float*)d_in[4];  // [1,A,4] f32
    float* out = (float*)d_out;
    float* ws  = (float*)d_ws;

    hipMemsetAsync(ws, 0, 3 * NB * sizeof(float), stream);

    dim3 gA((NA + 255) / 256, NB);
    assign_kernel<<<gA, 256, 0, stream>>>(boxes, labels, regression, cls,
                                          anchors, ws);
    dim3 gB(256, NB);  // 2048 blocks -> 8 blocks/CU, full occupancy for BW
    cls_neg_kernel<<<gB, 256, 0, stream>>>(cls, ws);
    finalize_kernel<<<1, 64, 0, stream>>>(ws, out);
}

// Round 2
// 235.439 us; speedup vs baseline: 1.1675x; 1.1675x over previous
//
#include <hip/hip_runtime.h>
#include <cmath>

#define NB 8
#define NA 49104
#define NM 50
#define NC 90
#define NBLK 192  // ceil(NA/256)

// ws layout (floats):
//   [0             .. NB*NBLK)    cls partials (neg sum + correction)
//   [NB*NBLK       .. 2*NB*NBLK)  reg partials
//   [2*NB*NBLK     .. 3*NB*NBLK)  num_pos partials
// All slots are overwritten every launch (no init required, atomics-free).

__device__ __forceinline__ float clipc(float x) {
    return fminf(fmaxf(x, 1e-4f), 1.0f - 1e-4f);
}

__device__ __forceinline__ float negterm(float x) {
    const float c = clipc(x);
    return 0.75f * c * c * (-__logf(1.0f - c));
}

// Block reduction: wave64 shuffle then LDS across waves. Valid on tid 0.
__device__ __forceinline__ float block_reduce(float v, float* red) {
#pragma unroll
    for (int o = 32; o > 0; o >>= 1) v += __shfl_down(v, o, 64);
    const int wave = threadIdx.x >> 6;
    const int lane = threadIdx.x & 63;
    if (lane == 0) red[wave] = v;
    __syncthreads();
    float r = 0.f;
    if (threadIdx.x == 0) {
        const int nw = blockDim.x >> 6;
        for (int w = 0; w < nw; ++w) r += red[w];
    }
    __syncthreads();  // allow red reuse by a later call
    return r;
}

// One block = 256 consecutive anchors of one sample. Does assignment +
// smooth-L1 AND streams the block's own contiguous cls slice for the
// negative focal sum (single pass over the 141 MB tensor, coalesced).
__global__ __launch_bounds__(256) void fused_kernel(
    const float* __restrict__ boxes,      // [B,M,4] x1y1x2y2
    const int*   __restrict__ labels,     // [B,M], 0 = padding
    const float* __restrict__ regression, // [B,A,4]
    const float* __restrict__ cls,        // [B,A,C]
    const float* __restrict__ anchors,    // [A,4] y1x1y2x2
    float* __restrict__ ws) {
    __shared__ float4 sbox[NM];
    __shared__ float  sarea[NM];
    __shared__ int    slab[NM];
    __shared__ float  red[4];

    const int b  = blockIdx.y;
    const int t  = threadIdx.x;
    const int a0 = blockIdx.x << 8;

    if (t < NM) {
        float4 bx = ((const float4*)boxes)[b * NM + t];
        const int l = labels[b * NM + t];
        float area = (bx.z - bx.x) * (bx.w - bx.y);
        if (l == 0) {
            // Invalid box: degenerate coords force inter=0 -> iou=0.
            // Output-equivalent to the reference's -1 mask (0 < 0.15 so
            // pos=false; ties at 0 only matter when !pos, where alab and
            // assigned are unused).
            bx.x = bx.y = bx.z = bx.w = 3e38f;
            area = 0.f;
        }
        sbox[t]  = bx;
        sarea[t] = area;
        slab[t]  = (l != 0) ? (l - 1) : 0;
    }
    __syncthreads();

    float corr = 0.f, regs = 0.f, npos = 0.f;
    const int a = a0 + t;
    if (a < NA) {
        const float4 an = ((const float4*)anchors)[a];
        const float ay1 = an.x, ax1 = an.y, ay2 = an.z, ax2 = an.w;
        const float aarea = (ay2 - ay1) * (ax2 - ax1);

        float best = -1.f;
        int arg = 0;
        for (int m = 0; m < NM; ++m) {
            const float4 bx = sbox[m];  // broadcast, conflict-free
            float iw = fminf(ax2, bx.z) - fmaxf(ax1, bx.x);
            float ih = fminf(ay2, bx.w) - fmaxf(ay1, bx.y);
            iw = fmaxf(iw, 0.f);
            ih = fmaxf(ih, 0.f);
            const float inter = iw * ih;
            const float ua = fmaxf(aarea + sarea[m] - inter, 1e-8f);
            const float iou = inter / ua;
            if (iou > best) { best = iou; arg = m; }  // first-occurrence
        }

        const bool big = sarea[arg] > 100.0f;
        const bool pos = big ? (best >= 0.5f) : (best >= 0.15f);
        if (pos) {
            npos = 1.f;
            const float4 bx = sbox[arg];
            const float aw = ax2 - ax1, ah = ay2 - ay1;
            const float acx = ax1 + 0.5f * aw, acy = ay1 + 0.5f * ah;
            const float gw0 = bx.z - bx.x, gh0 = bx.w - bx.y;
            const float gcx = bx.x + 0.5f * gw0, gcy = bx.y + 0.5f * gh0;
            const float gw = fmaxf(gw0, 1.f), gh = fmaxf(gh0, 1.f);
            const float4 r = ((const float4*)regression)[b * NA + a];
            const float d0 = fabsf((gcy - acy) / ah - r.x);
            const float d1 = fabsf((gcx - acx) / aw - r.y);
            const float d2 = fabsf(__logf(gh / ah) - r.z);
            const float d3 = fabsf(__logf(gw / aw) - r.w);
            regs  = (d0 <= 1.f / 9.f) ? 4.5f * d0 * d0 : d0 - (0.5f / 9.f);
            regs += (d1 <= 1.f / 9.f) ? 4.5f * d1 * d1 : d1 - (0.5f / 9.f);
            regs += (d2 <= 1.f / 9.f) ? 4.5f * d2 * d2 : d2 - (0.5f / 9.f);
            regs += (d3 <= 1.f / 9.f) ? 4.5f * d3 * d3 : d3 - (0.5f / 9.f);

            // replace neg term with pos term at (a, alab)
            const int alab = slab[arg];
            const float c = clipc(cls[((size_t)b * NA + a) * NC + alab]);
            const float omc = 1.f - c;
            corr = 0.25f * omc * omc * (-__logf(c)) -
                   0.75f * c * c * (-__logf(omc));
        }
    }

    // Streaming negative-term sum over this block's contiguous cls slice:
    // anchors [a0, aend) x 90 classes. Offsets/lengths are all 4-float
    // aligned (90*256 and 90*208 divisible by 4; base offsets div by 4).
    const int aend = (a0 + 256 < NA) ? a0 + 256 : NA;
    const int n4 = ((aend - a0) * NC) >> 2;
    const float4* p = (const float4*)(cls + ((size_t)b * NA + a0) * NC);
    float neg = 0.f;
    for (int i = t; i < n4; i += 256) {
        const float4 v = p[i];
        neg += negterm(v.x) + negterm(v.y) + negterm(v.z) + negterm(v.w);
    }

    const float tc = block_reduce(neg + corr, red);
    const float tr = block_reduce(regs, red);
    const float tn = block_reduce(npos, red);
    if (t == 0) {
        const int idx = b * NBLK + blockIdx.x;
        ws[idx]                 = tc;
        ws[NB * NBLK + idx]     = tr;
        ws[2 * NB * NBLK + idx] = tn;
    }
}

__global__ __launch_bounds__(256) void finalize_kernel(
    const float* __restrict__ ws, float* __restrict__ out) {
    __shared__ float red[4];
    const int t = threadIdx.x;
    float cl = 0.f, rl = 0.f;
    for (int b = 0; b < NB; ++b) {
        const float vc = (t < NBLK) ? ws[b * NBLK + t] : 0.f;
        const float vr = (t < NBLK) ? ws[NB * NBLK + b * NBLK + t] : 0.f;
        const float vn = (t < NBLK) ? ws[2 * NB * NBLK + b * NBLK + t] : 0.f;
        const float sc = block_reduce(vc, red);
        const float sr = block_reduce(vr, red);
        const float sn = block_reduce(vn, red);
        if (t == 0) {
            cl += sc / fmaxf(sn, 1.f);
            rl += (sn > 0.f) ? sr / (sn * 4.f) : 0.f;
        }
    }
    if (t == 0) {
        out[0] = cl / (float)NB;
        out[1] = rl / (float)NB * 50.f;
    }
}

extern "C" void kernel_launch(void* const* d_in, const int* in_sizes, int n_in,
                              void* d_out, int out_size, void* d_ws,
                              size_t ws_size, hipStream_t stream) {
    const float* boxes      = (const float*)d_in[0];  // [B,M,4] f32
    const int*   labels     = (const int*)d_in[1];    // [B,M] i32
    const float* regression = (const float*)d_in[2];  // [B,A,4] f32
    const float* cls        = (const float*)d_in[3];  // [B,A,C] f32
    const float* anchors    = (const float*)d_in[4];  // [1,A,4] f32
    float* out = (float*)d_out;
    float* ws  = (float*)d_ws;

    dim3 g(NBLK, NB);  // 1536 blocks, 6/CU, 24 waves/CU
    fused_kernel<<<g, 256, 0, stream>>>(boxes, labels, regression, cls,
                                        anchors, ws);
    finalize_kernel<<<1, 256, 0, stream>>>(ws, out);
}